// Round 12
// baseline (92.917 us; speedup 1.0000x reference)
//
#include <hip/hip_runtime.h>

#define IN_F   4096
#define OUT_F  4096
#define BATCH  512
#define NCONN  64
#define BT     4       // batch rows per block
#define OGRP   1024    // output features per block (1 per thread)
#define NTHR   1024

typedef unsigned short u16;
typedef _Float16 h4v __attribute__((ext_vector_type(4)));   // 8 B granule

// ---------------- Kernel 1: transpose+cvt x (B, IN_F) f32 -> xTh (IN_F, B) fp16 ----
__global__ __launch_bounds__(256) void transpose_kernel(const float* __restrict__ x,
                                                        _Float16* __restrict__ xTh) {
    __shared__ float tile[64 * 68];
    const int j0 = blockIdx.x * 64;
    const int b0 = blockIdx.y * 64;
    const int t  = threadIdx.x;
    const int c  = t & 15;
    const int r0 = t >> 4;
#pragma unroll
    for (int it = 0; it < 4; ++it) {
        const int r  = r0 + it * 16;
        const int pc = (4 * c) ^ (((r >> 2) & 7) << 2);
        const float4 v = *reinterpret_cast<const float4*>(
            x + (size_t)(b0 + r) * IN_F + j0 + 4 * c);
        *reinterpret_cast<float4*>(&tile[r * 68 + pc]) = v;
    }
    __syncthreads();
#pragma unroll
    for (int it = 0; it < 4; ++it) {
        const int jj = r0 + it * 16;
        h4v v;
#pragma unroll
        for (int i = 0; i < 4; ++i) {
            const int rr   = 4 * c + i;
            const int pcol = jj ^ (((rr >> 2) & 7) << 2);
            v[i] = (_Float16)tile[rr * 68 + pcol];
        }
        *reinterpret_cast<h4v*>(xTh + (size_t)(j0 + jj) * BATCH + b0 + 4 * c) = v;
    }
}

// ---------------- Kernel 2: connT[k][o] = conn[o][k] ----------------
__global__ __launch_bounds__(256) void connT_kernel(const int* __restrict__ conn,
                                                    int* __restrict__ connT) {
    __shared__ int tile[64][65];
    const int o0 = blockIdx.x * 64;
    const int tx = threadIdx.x & 63;
    const int ty = threadIdx.x >> 6;
#pragma unroll
    for (int r = 0; r < 16; ++r) {
        const int row = ty * 16 + r;
        tile[row][tx] = conn[(size_t)(o0 + row) * NCONN + tx];
    }
    __syncthreads();
#pragma unroll
    for (int r = 0; r < 16; ++r) {
        const int k = ty * 16 + r;
        connT[(size_t)k * OUT_F + o0 + tx] = tile[tx][k];
    }
}

// ---------------- Kernel 3: hybrid LDS + L2 gather ----------------
// Block: 4 batch rows x 1024 o's; 512 blocks -> 2/CU, 32 waves/CU (HW max).
// Each thread: 32 k's from LDS slice + 32 k's from global xTh (L2-resident).
// Odd/even waves swap phase order so both pipes stay loaded.
__global__ __launch_bounds__(NTHR, 8) void agg_kernel(const float* __restrict__ x,
                                                      const _Float16* __restrict__ xTh,
                                                      const int* __restrict__ connT,
                                                      const int* __restrict__ opidx,
                                                      float* __restrict__ out) {
    __shared__ alignas(16) _Float16 xs[IN_F * BT];   // [j][b], 32 KB

    const int bid   = blockIdx.x;
    const int btile = (bid & 7) * 16 + (bid >> 5);   // 0..127 (XCD-affine)
    const int og    = (bid >> 3) & 3;                // 0..3
    const int o0    = og * OGRP;
    const int b0    = btile * BT;
    const int t     = threadIdx.x;

    // ---- stage x slice -> LDS fp16 [j][b] (round-8 proven pattern) ----
    const int bb   = t & 3;
    const int joff = t >> 2;                         // 0..255
    const float* __restrict__ xrow = x + (size_t)(b0 + bb) * IN_F;
#pragma unroll 4
    for (int it = 0; it < 16; ++it) {
        const int j = it * 256 + joff;
        xs[j * BT + bb] = (_Float16)xrow[j];
    }
    __syncthreads();

    const int o = o0 + t;
    const int* __restrict__ cp = connT + o;
    const h4v* __restrict__ xs4 = reinterpret_cast<const h4v*>(xs);
    const h4v* __restrict__ xg  = reinterpret_cast<const h4v*>(xTh) + (b0 >> 2);

    float s0 = 0.f, s1 = 0.f, s2 = 0.f, s3 = 0.f;
    const _Float16 HNEG = __builtin_bit_cast(_Float16, (u16)0xFC00);
    const _Float16 HPOS = __builtin_bit_cast(_Float16, (u16)0x7C00);
    h4v hx = {HNEG, HNEG, HNEG, HNEG};
    h4v hn = {HPOS, HPOS, HPOS, HPOS};

#define CONSUME(gq)                                                         \
    do {                                                                    \
        hx = __builtin_elementwise_max(hx, (gq));                           \
        hn = __builtin_elementwise_min(hn, (gq));                           \
        s0 = fmaf((float)(gq)[0], 1.0f, s0);                                \
        s1 = fmaf((float)(gq)[1], 1.0f, s1);                                \
        s2 = fmaf((float)(gq)[2], 1.0f, s2);                                \
        s3 = fmaf((float)(gq)[3], 1.0f, s3);                                \
    } while (0)

    // ---- LDS half: 32 k's starting at k0, 8-deep pipeline ----
    auto lds_phase = [&](int k0) {
        int idx[8];
#pragma unroll
        for (int q = 0; q < 8; ++q) idx[q] = cp[(size_t)(k0 + q) * OUT_F];
        for (int kb = 0; kb < 32; kb += 8) {
            h4v g[8];
#pragma unroll
            for (int q = 0; q < 8; ++q) g[q] = xs4[idx[q]];        // ds_read_b64
            if (kb + 8 < 32) {
#pragma unroll
                for (int q = 0; q < 8; ++q)
                    idx[q] = cp[(size_t)(k0 + kb + 8 + q) * OUT_F];
            }
#pragma unroll
            for (int q = 0; q < 8; ++q) CONSUME(g[q]);
        }
    };

    // ---- global half: 32 k's starting at k0, 8-deep pipeline ----
    auto glob_phase = [&](int k0) {
        int idx[8];
#pragma unroll
        for (int q = 0; q < 8; ++q) idx[q] = cp[(size_t)(k0 + q) * OUT_F];
        for (int kb = 0; kb < 32; kb += 8) {
            h4v g[8];
#pragma unroll
            for (int q = 0; q < 8; ++q)
                g[q] = xg[(size_t)idx[q] * (BATCH / 4)];           // 8 B from L2
            if (kb + 8 < 32) {
#pragma unroll
                for (int q = 0; q < 8; ++q)
                    idx[q] = cp[(size_t)(k0 + kb + 8 + q) * OUT_F];
            }
#pragma unroll
            for (int q = 0; q < 8; ++q) CONSUME(g[q]);
        }
    };

    if ((t >> 6) & 1) { lds_phase(0);  glob_phase(32); }
    else              { glob_phase(0); lds_phase(32);  }
#undef CONSUME

    const float sv[4] = {s0, s1, s2, s3};
    const float xv[4] = {(float)hx[0], (float)hx[1], (float)hx[2], (float)hx[3]};
    const float nv[4] = {(float)hn[0], (float)hn[1], (float)hn[2], (float)hn[3]};

    // ---- epilogue: scalar NT stores, coalesced along o ----
    const int op = opidx[o];
    float* __restrict__ fwd  = out;                          // (B, OUT_F)
    float* __restrict__ outp = out + (size_t)BATCH * OUT_F;  // (B, 4, OUT_F)

#pragma unroll
    for (int i = 0; i < 4; ++i) {
        const float ss = sv[i];
        const float mm = ss * 0.015625f;
        const float hxv = xv[i];
        const float lnv = nv[i];
        const float fw = (op == 0) ? mm : (op == 1) ? ss : (op == 2) ? hxv : lnv;
        const size_t rowO = (size_t)(b0 + i) * (4 * OUT_F) + o;
        __builtin_nontemporal_store(fw, fwd + (size_t)(b0 + i) * OUT_F + o);
        __builtin_nontemporal_store(mm, outp + rowO);
        __builtin_nontemporal_store(ss, outp + rowO + OUT_F);
        __builtin_nontemporal_store(hxv, outp + rowO + 2 * OUT_F);
        __builtin_nontemporal_store(lnv, outp + rowO + 3 * OUT_F);
    }
}

extern "C" void kernel_launch(void* const* d_in, const int* in_sizes, int n_in,
                              void* d_out, int out_size, void* d_ws, size_t ws_size,
                              hipStream_t stream) {
    const float* x     = (const float*)d_in[0];
    const int*   conn  = (const int*)d_in[1];
    const int*   opidx = (const int*)d_in[2];
    float*       out   = (float*)d_out;
    _Float16*    xTh   = (_Float16*)d_ws;                    // 4 MiB
    int*         connT = (int*)((char*)d_ws + (size_t)IN_F * BATCH * 2);  // 1 MiB

    connT_kernel<<<OUT_F / 64, 256, 0, stream>>>(conn, connT);
    dim3 tg(IN_F / 64, BATCH / 64);
    transpose_kernel<<<tg, 256, 0, stream>>>(x, xTh);

    const int nblocks = (BATCH / BT) * (OUT_F / OGRP);   // 512
    agg_kernel<<<nblocks, NTHR, 0, stream>>>(x, xTh, connT, opidx, out);
}